// Round 8
// baseline (183.466 us; speedup 1.0000x reference)
//
#include <hip/hip_runtime.h>
#include <math.h>

#define N   512
#define M   256
#define A   128
#define HS  512
#define C   512

// ---------------- workspace layout (float offsets) ----------------
// Live ranges verified disjoint for aliases:
//  XS  (prep->ggemm)   aliases H+HEADS head (H written by k_act AFTER ggemm)
//  GI  (ggemm->act)    aliases SIMR+SIMW+SHIFT (written by k_sim/rowsoft, later)
#define WS_H       0          // [512*512] h fp32 (written by k_act)
#define WS_HEADS   262144     // [512*1024] keys|shift logits fp32
#define WS_SIMR    786432     // [512*512]; wgr in-place later
#define WS_SIMW    1048576
#define WS_SHIFT   1310720
#define WS_WGRT    1572864
#define WS_WGWT    1835008
#define WS_SHIFTT  2097152
#define WS_CIRCTR  2359296
#define WS_CIRCTW  2621440
#define WS_MEMTS   2883584    // [256][512] slots: pre-split bf16 memory^T
#define WS_G       3014656
#define WS_GAMMA   3015168
#define WS_INVM    3015680
#define WS_INVKR   3016192
#define WS_INVKW   3016704
#define WS_CSR     3017216
#define WS_CSW     3017728
#define WS_XS      0          // [512][640] slots: pre-split concat(action,hidden); alias
#define WS_GI      786432     // [512*1536] GRU pre-activation; alias

#define LD4(p) (*reinterpret_cast<const float4*>(p))
#define LD2(p) (*reinterpret_cast<const float2*>(p))

typedef short bf16x8 __attribute__((ext_vector_type(8)));
typedef float f32x16 __attribute__((ext_vector_type(16)));

struct HiLo { bf16x8 hi, lo; };

// x = hi + lo, hi = trunc-bf16(x), lo = trunc-bf16(x - hi); x*y ~= hh + hl + lh.
__device__ __forceinline__ HiLo split8(const float4 u, const float4 v) {
  const float x[8] = {u.x, u.y, u.z, u.w, v.x, v.y, v.z, v.w};
  union { unsigned int w[4]; bf16x8 v; } H, L;
#pragma unroll
  for (int d = 0; d < 4; ++d) {
    const unsigned int a = __float_as_uint(x[2 * d]);
    const unsigned int b = __float_as_uint(x[2 * d + 1]);
    H.w[d] = (a >> 16) | (b & 0xFFFF0000u);
    const float la = x[2 * d]     - __uint_as_float(a & 0xFFFF0000u);
    const float lb = x[2 * d + 1] - __uint_as_float(b & 0xFFFF0000u);
    L.w[d] = (__float_as_uint(la) >> 16) | (__float_as_uint(lb) & 0xFFFF0000u);
  }
  HiLo r; r.hi = H.v; r.lo = L.v;
  return r;
}

// Pre-split operand: the two float4s ARE the (hi, lo) bf16x8 pair bit-wise.
__device__ __forceinline__ HiLo reint8(const float4 q0, const float4 q1) {
  HiLo r;
  r.hi = *reinterpret_cast<const bf16x8*>(&q0);
  r.lo = *reinterpret_cast<const bf16x8*>(&q1);
  return r;
}

__device__ __forceinline__ f32x16 mm3(const HiLo& a, const HiLo& b, f32x16 acc) {
  acc = __builtin_amdgcn_mfma_f32_32x32x16_bf16(a.hi, b.hi, acc, 0, 0, 0);
  acc = __builtin_amdgcn_mfma_f32_32x32x16_bf16(a.hi, b.lo, acc, 0, 0, 0);
  acc = __builtin_amdgcn_mfma_f32_32x32x16_bf16(a.lo, b.hi, acc, 0, 0, 0);
  return acc;
}

// One wave = one 32x32 tile. pa/pb pre-offset by row*ld + koff.
// Two named pipeline slots (E/O) -> no runtime-indexed arrays (stays in VGPRs);
// loads for step ks+2 issue while step ks computes (2-deep, latency hiding).
template <int NK, bool SA, bool SB>
__device__ __forceinline__ f32x16 tileMM(const float* __restrict__ pa,
                                         const float* __restrict__ pb) {
  f32x16 acc;
#pragma unroll
  for (int t = 0; t < 16; ++t) acc[t] = 0.0f;
  float4 aE0 = LD4(pa), aE1 = LD4(pa + 4);
  float4 bE0 = LD4(pb), bE1 = LD4(pb + 4);
  float4 aO0, aO1, bO0, bO1;
  if (NK > 1) {
    aO0 = LD4(pa + 16); aO1 = LD4(pa + 20);
    bO0 = LD4(pb + 16); bO1 = LD4(pb + 20);
  }
#pragma unroll
  for (int ks = 0; ks < NK; ++ks) {
    HiLo Af, Bf;
    if ((ks & 1) == 0) {
      Af = SA ? reint8(aE0, aE1) : split8(aE0, aE1);
      Bf = SB ? reint8(bE0, bE1) : split8(bE0, bE1);
      if (ks + 2 < NK) {
        const int k = (ks + 2) * 16;
        aE0 = LD4(pa + k); aE1 = LD4(pa + k + 4);
        bE0 = LD4(pb + k); bE1 = LD4(pb + k + 4);
      }
    } else {
      Af = SA ? reint8(aO0, aO1) : split8(aO0, aO1);
      Bf = SB ? reint8(bO0, bO1) : split8(bO0, bO1);
      if (ks + 2 < NK) {
        const int k = (ks + 2) * 16;
        aO0 = LD4(pa + k); aO1 = LD4(pa + k + 4);
        bO0 = LD4(pb + k); bO1 = LD4(pb + k + 4);
      }
    }
    acc = mm3(Af, Bf, acc);
  }
  return acc;
}

#define ACC_ROW(t, lane) (((t) & 3) + 8 * ((t) >> 2) + 4 * ((lane) >> 5))

// ---------------- 0. prep: pre-split concat(action,hidden) -> xs ----------------
// xs[row][group g of 8]: 16B hi + 16B lo; float-slot addr = row*640 + g*8
// (identical pointer arithmetic as the fp32 operand it replaces).
__global__ __launch_bounds__(256) void k_prep(const float* __restrict__ action,
                                              const float* __restrict__ hidden,
                                              float* __restrict__ xs) {
  const int idx = blockIdx.x * 256 + threadIdx.x;   // 40960 groups
  const int row = idx / 80, g = idx % 80;
  const float* src = (g < 16) ? (action + row * 128 + g * 8)
                              : (hidden + row * 512 + (g - 16) * 8);
  const HiLo s = split8(LD4(src), LD4(src + 4));
  *reinterpret_cast<float4*>(xs + idx * 8)     = *reinterpret_cast<const float4*>(&s.hi);
  *reinterpret_cast<float4*>(xs + idx * 8 + 4) = *reinterpret_cast<const float4*>(&s.lo);
}

// ---------------- 0b. memory^T, pre-split -> memTs ----------------
__global__ __launch_bounds__(256) void k_memT(const float* __restrict__ mem,
                                              float* __restrict__ memTs) {
  __shared__ float tile[32][33];
  const int bx = blockIdx.x, by = blockIdx.y, tx = threadIdx.x, ty = threadIdx.y;
#pragma unroll
  for (int k2 = 0; k2 < 4; ++k2)
    tile[ty + 8 * k2][tx] = mem[(by * 32 + ty + 8 * k2) * 256 + bx * 32 + tx];
  __syncthreads();
  // memT[bx*32+tx][by*32+b] = tile[b][tx]; pack groups of 8 along b.
  if (ty < 4) {
    float4 q0, q1;
    q0.x = tile[8 * ty + 0][tx]; q0.y = tile[8 * ty + 1][tx];
    q0.z = tile[8 * ty + 2][tx]; q0.w = tile[8 * ty + 3][tx];
    q1.x = tile[8 * ty + 4][tx]; q1.y = tile[8 * ty + 5][tx];
    q1.z = tile[8 * ty + 6][tx]; q1.w = tile[8 * ty + 7][tx];
    const HiLo s = split8(q0, q1);
    float* dst = memTs + (bx * 32 + tx) * 512 + (by * 4 + ty) * 8;
    *reinterpret_cast<float4*>(dst)     = *reinterpret_cast<const float4*>(&s.hi);
    *reinterpret_cast<float4*>(dst + 4) = *reinterpret_cast<const float4*>(&s.lo);
  }
}

// ---------------- 1. GRU GEMM (plain 512x1536x640): gi = x @ W_ih^T ----------------
// 768 waves; XCD-grouped swizzle: blocks sharing a W column-tile land on one XCD.
__global__ __launch_bounds__(64) void k_ggemm(const float* __restrict__ xs,
                                              const float* __restrict__ W_ih,
                                              float* __restrict__ gi) {
  const int lane = threadIdx.x;
  const int wg = blockIdx.x;                 // 0..767
  const int xcd = wg & 7, inner = wg >> 3;   // inner 0..95
  const int bi = inner & 15;
  const int bc = xcd * 6 + (inner >> 4);     // 0..47
  const int r0 = bi * 32, c0 = bc * 32;
  const int m = lane & 31, koff = (lane >> 5) * 8;
  const f32x16 acc = tileMM<40, true, false>(xs + (r0 + m) * 640 + koff,
                                             W_ih + (c0 + m) * 640 + koff);
  const int col = c0 + m;
#pragma unroll
  for (int t = 0; t < 16; ++t)
    gi[(r0 + ACC_ROW(t, lane)) * 1536 + col] = acc[t];
}

// ---------------- 2. GRU activation (round-2 proven) ----------------
__global__ __launch_bounds__(256) void k_act(const float* __restrict__ gi,
                                             const float* __restrict__ b_ih,
                                             const float* __restrict__ b_hh,
                                             float* __restrict__ h) {
  const int idx = blockIdx.x * 256 + threadIdx.x;
  const int b = idx >> 7, c4 = (idx & 127) * 4;
  const float4 g0 = LD4(gi + b * 1536 + c4);
  const float4 g1 = LD4(gi + b * 1536 + 512 + c4);
  const float4 g2 = LD4(gi + b * 1536 + 1024 + c4);
  const float4 bi0 = LD4(b_ih + c4);
  const float4 bi1 = LD4(b_ih + 512 + c4);
  const float4 bi2 = LD4(b_ih + 1024 + c4);
  const float4 bh0 = LD4(b_hh + c4);
  const float4 bh1 = LD4(b_hh + 512 + c4);
  const float4 bh2 = LD4(b_hh + 1024 + c4);
  const float gr[4] = {g0.x + bi0.x + bh0.x, g0.y + bi0.y + bh0.y, g0.z + bi0.z + bh0.z, g0.w + bi0.w + bh0.w};
  const float gz[4] = {g1.x + bi1.x + bh1.x, g1.y + bi1.y + bh1.y, g1.z + bi1.z + bh1.z, g1.w + bi1.w + bh1.w};
  const float gn[4] = {g2.x + bi2.x, g2.y + bi2.y, g2.z + bi2.z, g2.w + bi2.w};
  const float hn[4] = {bh2.x, bh2.y, bh2.z, bh2.w};
  float res[4];
#pragma unroll
  for (int u = 0; u < 4; ++u) {
    const float r = 1.0f / (1.0f + expf(-gr[u]));
    const float z = 1.0f / (1.0f + expf(-gz[u]));
    res[u] = (1.0f - z) * tanhf(gn[u] + r * hn[u]);
  }
  float4 o; o.x = res[0]; o.y = res[1]; o.z = res[2]; o.w = res[3];
  *reinterpret_cast<float4*>(h + b * 512 + c4) = o;
}

// ---------------- 3. heads GEMM: read|write keys + shift logits ----------------
__global__ __launch_bounds__(64) void k_heads(const float* __restrict__ h,
                                              const float* __restrict__ W_read, const float* __restrict__ b_read,
                                              const float* __restrict__ W_write, const float* __restrict__ b_write,
                                              const float* __restrict__ W_shift, const float* __restrict__ b_shift,
                                              float* __restrict__ heads) {
  const int lane = threadIdx.x;
  const int wg = blockIdx.x;                 // 0..511
  const int xcd = wg & 7, inner = wg >> 3;   // inner 0..63
  const int bi = inner & 15;
  const int bn = xcd * 4 + (inner >> 4);     // 0..31
  const int r0 = bi * 32, n0 = bn * 32;
  const float* W;
  const float* bias;
  if (n0 < 256)      { W = W_read  + n0 * 512;         bias = b_read  + n0; }
  else if (n0 < 512) { W = W_write + (n0 - 256) * 512; bias = b_write + (n0 - 256); }
  else               { W = W_shift + (n0 - 512) * 512; bias = b_shift + (n0 - 512); }
  const int m = lane & 31, koff = (lane >> 5) * 8;
  const f32x16 acc = tileMM<32, false, false>(h + (r0 + m) * 512 + koff,
                                              W + m * 512 + koff);
  const int col = lane & 31;
  const float bv = bias[col];
#pragma unroll
  for (int t = 0; t < 16; ++t)
    heads[(r0 + ACC_ROW(t, lane)) * 1024 + n0 + col] = acc[t] + bv;
}

// ---------------- 4. gate/gamma + inverse norms ----------------
__global__ __launch_bounds__(64) void k_ggnorms(const float* __restrict__ h,
                                                const float* __restrict__ W_gate, const float* __restrict__ b_gate,
                                                const float* __restrict__ W_gamma, const float* __restrict__ b_gamma,
                                                const float* __restrict__ memory,
                                                const float* __restrict__ heads,
                                                float* __restrict__ g, float* __restrict__ gamma,
                                                float* __restrict__ invm, float* __restrict__ invkr,
                                                float* __restrict__ invkw) {
  const int r = blockIdx.x, t = threadIdx.x;
  if (r < 512) {
    float ag = 0.f, am = 0.f;
#pragma unroll
    for (int u = 0; u < 8; ++u) {
      const float hv = h[r * 512 + t + 64 * u];
      ag = fmaf(hv, W_gate[t + 64 * u], ag);
      am = fmaf(hv, W_gamma[t + 64 * u], am);
    }
    for (int o = 32; o > 0; o >>= 1) { ag += __shfl_down(ag, o); am += __shfl_down(am, o); }
    if (t == 0) {
      g[r] = 1.0f / (1.0f + expf(-(ag + b_gate[0])));
      const float x = am + b_gamma[0];
      gamma[r] = (x > 0.f) ? (x + log1pf(expf(-x))) : log1pf(expf(x));
    }
    return;
  }
  float ss;
  float* dst;
  if (r < 1024) {
    const float4 v = LD4(memory + (r - 512) * 256 + t * 4);
    ss = v.x * v.x + v.y * v.y + v.z * v.z + v.w * v.w;
    dst = invm + (r - 512);
  } else {
    const int row = (r < 1536) ? (r - 1024) : (r - 1536);
    const int seg = (r < 1536) ? 0 : 256;
    const float4 v = LD4(heads + row * 1024 + seg + t * 4);
    ss = v.x * v.x + v.y * v.y + v.z * v.z + v.w * v.w;
    dst = ((r < 1536) ? invkr : invkw) + row;
  }
  for (int o = 32; o > 0; o >>= 1) ss += __shfl_down(ss, o);
  if (t == 0) *dst = 1.0f / (sqrtf(ss) + 1e-16f);
}

// ---------------- 5. similarity GEMM ----------------
__global__ __launch_bounds__(64) void k_sim(const float* __restrict__ memory,
                                            const float* __restrict__ heads,
                                            float* __restrict__ simR, float* __restrict__ simW) {
  const int lane = threadIdx.x;
  const int i0 = blockIdx.x * 32;
  const int b0 = blockIdx.y * 32;
  const int seg = blockIdx.z ? 256 : 0;
  float* out = blockIdx.z ? simW : simR;
  const int m = lane & 31, koff = (lane >> 5) * 8;
  const f32x16 acc = tileMM<16, false, false>(memory + (i0 + m) * 256 + koff,
                                              heads + (b0 + m) * 1024 + seg + koff);
  const int col = lane & 31;
#pragma unroll
  for (int t = 0; t < 16; ++t)
    out[(i0 + ACC_ROW(t, lane)) * 512 + b0 + col] = acc[t];
}

// ---------------- 6. row softmax (+cosine scale, +gate mix) / shift softmax ----------------
__global__ __launch_bounds__(256) void k_rowsoft(const float* __restrict__ simR, const float* __restrict__ simW,
                                                 const float* __restrict__ heads,
                                                 const float* __restrict__ invm, const float* __restrict__ invkr,
                                                 const float* __restrict__ invkw, const float* __restrict__ g,
                                                 const float* __restrict__ prevR, const float* __restrict__ prevW,
                                                 float* __restrict__ wgr, float* __restrict__ wgw,
                                                 float* __restrict__ shift_nat) {
  __shared__ float red[8];
  const int row = blockIdx.x, mode = blockIdx.y, t = threadIdx.x;
  float v0, v1;
  if (mode == 2) {
    const float2 s = LD2(heads + row * 1024 + 512 + 2 * t);
    v0 = s.x; v1 = s.y;
  } else {
    const float* sim = mode ? simW : simR;
    const float* invk = mode ? invkw : invkr;
    const float2 s = LD2(sim + row * 512 + 2 * t);
    const float sc = invm[row];
    v0 = s.x * sc * invk[2 * t];
    v1 = s.y * sc * invk[2 * t + 1];
  }
  float mx = fmaxf(v0, v1);
  for (int o = 32; o > 0; o >>= 1) mx = fmaxf(mx, __shfl_down(mx, o));
  if ((t & 63) == 0) red[t >> 6] = mx;
  __syncthreads();
  mx = fmaxf(fmaxf(red[0], red[1]), fmaxf(red[2], red[3]));
  const float e0 = expf(v0 - mx), e1 = expf(v1 - mx);
  float s2 = e0 + e1;
  for (int o = 32; o > 0; o >>= 1) s2 += __shfl_down(s2, o);
  if ((t & 63) == 0) red[4 + (t >> 6)] = s2;
  __syncthreads();
  const float S = (red[4] + red[5]) + (red[6] + red[7]);
  const float inv = 1.0f / S;
  const float p0 = e0 * inv, p1 = e1 * inv;
  if (mode == 2) {
    *reinterpret_cast<float2*>(shift_nat + row * 512 + 2 * t) = make_float2(p0, p1);
  } else {
    const float* prev = mode ? prevW : prevR;
    float* outw = mode ? wgw : wgr;
    const float gv = g[row];
    const float2 pr = LD2(prev + row * 512 + 2 * t);
    *reinterpret_cast<float2*>(outw + row * 512 + 2 * t) =
        make_float2(gv * p0 + (1.0f - gv) * pr.x, gv * p1 + (1.0f - gv) * pr.y);
  }
}

// ---------------- 7. transposes (wgr, wgw, shift) ----------------
__global__ __launch_bounds__(256) void k_transpose(const float* __restrict__ wgr, const float* __restrict__ wgw,
                                                   const float* __restrict__ shift_nat,
                                                   float* __restrict__ wgrT, float* __restrict__ wgwT,
                                                   float* __restrict__ shiftT) {
  __shared__ float tile[32][33];
  const int z = blockIdx.z;
  const float* src = (z == 0) ? wgr : (z == 1) ? wgw : shift_nat;
  float* dst = (z == 0) ? wgrT : (z == 1) ? wgwT : shiftT;
  const int bx = blockIdx.x, by = blockIdx.y, tx = threadIdx.x, ty = threadIdx.y;
#pragma unroll
  for (int k2 = 0; k2 < 4; ++k2)
    tile[ty + 8 * k2][tx] = src[(by * 32 + ty + 8 * k2) * 512 + bx * 32 + tx];
  __syncthreads();
#pragma unroll
  for (int k2 = 0; k2 < 4; ++k2)
    dst[(bx * 32 + ty + 8 * k2) * 512 + by * 32 + tx] = tile[tx][ty + 8 * k2];
}

// ---------------- 8. circular convolution + fused sharpen ----------------
__global__ __launch_bounds__(256) void k_circ(const float* __restrict__ wgrT, const float* __restrict__ wgwT,
                                              const float* __restrict__ shiftT,
                                              const float* __restrict__ gamma,
                                              float* __restrict__ circTR, float* __restrict__ circTW,
                                              float* __restrict__ csumR, float* __restrict__ csumW) {
  __shared__ float ls[4][1600];
  const int wid = threadIdx.x >> 6, lane = threadIdx.x & 63;
  const int b = blockIdx.x * 4 + wid;
  const float* wsrc = (blockIdx.y ? wgwT : wgrT) + b * 512;
  const float* ssrc = shiftT + b * 512;
  float* out = (blockIdx.y ? circTW : circTR) + b * 512;
  float* cs = blockIdx.y ? csumW : csumR;
  float* wl = ls[wid];
  float* sl = ls[wid] + 1056;

#pragma unroll
  for (int u = 0; u < 8; ++u) {
    const int k = lane + 64 * u;
    const float v = wsrc[k];
    wl[k + (k >> 5)] = v;
    const int k2 = k + 512;
    wl[k2 + (k2 >> 5)] = v;
    sl[k] = ssrc[k];
  }
  __syncthreads();

  const int i0 = lane * 8;
  float acc[8] = {};
  float win[8];
#pragma unroll
  for (int q = 0; q < 8; ++q) {
    const int a0 = i0 + 512 + q;
    win[q] = wl[a0 + (a0 >> 5)];
  }
  for (int jb = 0; jb < 512; jb += 8) {
    const float4 sA = LD4(&sl[jb]);
    const float4 sB = LD4(&sl[jb + 4]);
    const float sv[8] = {sA.x, sA.y, sA.z, sA.w, sB.x, sB.y, sB.z, sB.w};
#pragma unroll
    for (int u = 0; u < 8; ++u) {
      const float s = sv[u];
#pragma unroll
      for (int t = 0; t < 8; ++t) acc[t] = fmaf(win[(t - u) & 7], s, acc[t]);
      const int na = i0 + 511 - (jb + u);
      win[(7 - u) & 7] = wl[na + (na >> 5)];
    }
  }
  const float4 gm0 = LD4(gamma + i0);
  const float4 gm1 = LD4(gamma + i0 + 4);
  const float ge[8] = {gm0.x, gm0.y, gm0.z, gm0.w, gm1.x, gm1.y, gm1.z, gm1.w};
  float p[8];
  float local = 0.f;
#pragma unroll
  for (int q = 0; q < 8; ++q) { p[q] = powf(acc[q], ge[q]); local += p[q]; }
  *reinterpret_cast<float4*>(out + i0) = make_float4(p[0], p[1], p[2], p[3]);
  *reinterpret_cast<float4*>(out + i0 + 4) = make_float4(p[4], p[5], p[6], p[7]);
  for (int o = 32; o > 0; o >>= 1) local += __shfl_down(local, o);
  if (lane == 0) cs[b] = local;
}

// ---------------- 9. final weights: out[i,b] = p[b,i]/csum[b] ----------------
__global__ __launch_bounds__(256) void k_finalw(const float* __restrict__ circTR, const float* __restrict__ circTW,
                                                const float* __restrict__ csumR, const float* __restrict__ csumW,
                                                float* __restrict__ d_out) {
  __shared__ float tile[32][33];
  const int z = blockIdx.z;
  const float* src = z ? circTW : circTR;
  const float* cs = z ? csumW : csumR;
  float* dst = d_out + 131072 + z * 262144;
  const int bx = blockIdx.x, by = blockIdx.y, tx = threadIdx.x, ty = threadIdx.y;
#pragma unroll
  for (int k2 = 0; k2 < 4; ++k2) {
    const int r = by * 32 + ty + 8 * k2;
    tile[ty + 8 * k2][tx] = src[r * 512 + bx * 32 + tx] * (1.0f / cs[r]);
  }
  __syncthreads();
#pragma unroll
  for (int k2 = 0; k2 < 4; ++k2)
    dst[(bx * 32 + ty + 8 * k2) * 512 + by * 32 + tx] = tile[tx][ty + 8 * k2];
}

// ---------------- 10. read vector: rv = rw @ memory (split-K=2, atomic) ----------------
__global__ __launch_bounds__(64) void k_readvec(const float* __restrict__ rw,
                                                const float* __restrict__ memTs,
                                                float* __restrict__ rv) {
  const int lane = threadIdx.x;
  const int i0 = blockIdx.x * 32;
  const int m0 = blockIdx.y * 32;
  const int kz = blockIdx.z * 256;
  const int m = lane & 31, koff = (lane >> 5) * 8;
  const f32x16 acc = tileMM<16, false, true>(rw + (i0 + m) * 512 + kz + koff,
                                             memTs + (m0 + m) * 512 + kz + koff);
  const int col = lane & 31;
#pragma unroll
  for (int t = 0; t < 16; ++t)
    atomicAdd(&rv[(i0 + ACC_ROW(t, lane)) * 256 + m0 + col], acc[t]);
}

// ---------------- launcher ----------------
extern "C" void kernel_launch(void* const* d_in, const int* in_sizes, int n_in,
                              void* d_out, int out_size, void* d_ws, size_t ws_size,
                              hipStream_t stream) {
  const float* action  = (const float*)d_in[0];
  const float* hidden  = (const float*)d_in[1];
  const float* prevR   = (const float*)d_in[2];
  const float* prevW   = (const float*)d_in[3];
  const float* memory  = (const float*)d_in[4];
  const float* W_ih    = (const float*)d_in[5];
  const float* b_ih    = (const float*)d_in[7];
  const float* b_hh    = (const float*)d_in[8];
  const float* W_read  = (const float*)d_in[9];
  const float* b_read  = (const float*)d_in[10];
  const float* W_write = (const float*)d_in[11];
  const float* b_write = (const float*)d_in[12];
  const float* W_shift = (const float*)d_in[13];
  const float* b_shift = (const float*)d_in[14];
  const float* W_gamma = (const float*)d_in[15];
  const float* b_gamma = (const float*)d_in[16];
  const float* W_gate  = (const float*)d_in[17];
  const float* b_gate  = (const float*)d_in[18];

  float* ws = (float*)d_ws;
  float* out = (float*)d_out;

  // zero read_vector region (atomic target)
  hipMemsetAsync(out, 0, 131072 * sizeof(float), stream);

  k_prep<<<160, 256, 0, stream>>>(action, hidden, ws + WS_XS);
  k_memT<<<dim3(8, 16), dim3(32, 8), 0, stream>>>(memory, ws + WS_MEMTS);
  k_ggemm<<<768, 64, 0, stream>>>(ws + WS_XS, W_ih, ws + WS_GI);
  k_act<<<256, 256, 0, stream>>>(ws + WS_GI, b_ih, b_hh, ws + WS_H);
  k_heads<<<512, 64, 0, stream>>>(ws + WS_H, W_read, b_read, W_write, b_write,
                                  W_shift, b_shift, ws + WS_HEADS);
  k_ggnorms<<<2048, 64, 0, stream>>>(ws + WS_H, W_gate, b_gate, W_gamma, b_gamma,
                                     memory, ws + WS_HEADS,
                                     ws + WS_G, ws + WS_GAMMA,
                                     ws + WS_INVM, ws + WS_INVKR, ws + WS_INVKW);
  k_sim<<<dim3(16, 16, 2), 64, 0, stream>>>(memory, ws + WS_HEADS, ws + WS_SIMR, ws + WS_SIMW);
  k_rowsoft<<<dim3(512, 3), 256, 0, stream>>>(ws + WS_SIMR, ws + WS_SIMW, ws + WS_HEADS,
                                              ws + WS_INVM, ws + WS_INVKR, ws + WS_INVKW,
                                              ws + WS_G, prevR, prevW,
                                              ws + WS_SIMR, ws + WS_SIMW, ws + WS_SHIFT);
  k_transpose<<<dim3(16, 16, 3), dim3(32, 8), 0, stream>>>(ws + WS_SIMR, ws + WS_SIMW, ws + WS_SHIFT,
                                                           ws + WS_WGRT, ws + WS_WGWT, ws + WS_SHIFTT);
  k_circ<<<dim3(128, 2), 256, 0, stream>>>(ws + WS_WGRT, ws + WS_WGWT, ws + WS_SHIFTT,
                                           ws + WS_GAMMA,
                                           ws + WS_CIRCTR, ws + WS_CIRCTW,
                                           ws + WS_CSR, ws + WS_CSW);
  k_finalw<<<dim3(16, 16, 2), dim3(32, 8), 0, stream>>>(ws + WS_CIRCTR, ws + WS_CIRCTW,
                                                        ws + WS_CSR, ws + WS_CSW, out);
  k_readvec<<<dim3(16, 8, 2), 64, 0, stream>>>(out + 131072, ws + WS_MEMTS, out);
}

// Round 11
// 180.859 us; speedup vs baseline: 1.0144x; 1.0144x over previous
//
#include <hip/hip_runtime.h>
#include <math.h>

// ---------------- workspace layout (float offsets) ----------------
#define WS_H       0          // [512*512]  h
#define WS_HEADS   262144     // [512*1024] keys | shift logits
#define WS_SIMR    786432     // [512*512]
#define WS_SIMW    1048576    // [512*512]
#define WS_WGRT    1310720    // [512*512] transposed gated read weight
#define WS_WGWT    1572864
#define WS_SHIFTT  1835008    // [512*512] transposed shift softmax
#define WS_MEMTS   2097152    // [256][512] pre-split bf16 memory^T
#define WS_GI      2228224    // [512*1536] GRU pre-activation
#define WS_G       3014656    // [512]
#define WS_GAMMA   3015168    // [512]
#define WS_INVM    3015680    // [512]
#define WS_SSR     3016192    // [512] key sum-of-squares (read), atomic
#define WS_SSW     3016704    // [512]

#define LD4(p) (*reinterpret_cast<const float4*>(p))
#define LD2(p) (*reinterpret_cast<const float2*>(p))

typedef short bf16x8 __attribute__((ext_vector_type(8)));
typedef float f32x16 __attribute__((ext_vector_type(16)));

struct HiLo { bf16x8 hi, lo; };

// x = hi + lo, hi = trunc-bf16(x), lo = trunc-bf16(x - hi); x*y ~= hh + hl + lh.
__device__ __forceinline__ HiLo split8(const float4 u, const float4 v) {
  const float x[8] = {u.x, u.y, u.z, u.w, v.x, v.y, v.z, v.w};
  union { unsigned int w[4]; bf16x8 v; } H, L;
#pragma unroll
  for (int d = 0; d < 4; ++d) {
    const unsigned int a = __float_as_uint(x[2 * d]);
    const unsigned int b = __float_as_uint(x[2 * d + 1]);
    H.w[d] = (a >> 16) | (b & 0xFFFF0000u);
    const float la = x[2 * d]     - __uint_as_float(a & 0xFFFF0000u);
    const float lb = x[2 * d + 1] - __uint_as_float(b & 0xFFFF0000u);
    L.w[d] = (__float_as_uint(la) >> 16) | (__float_as_uint(lb) & 0xFFFF0000u);
  }
  HiLo r; r.hi = H.v; r.lo = L.v;
  return r;
}

// Pre-split operand: the two float4s ARE the (hi, lo) bf16x8 pair bit-wise.
__device__ __forceinline__ HiLo reint8(const float4 q0, const float4 q1) {
  HiLo r;
  r.hi = *reinterpret_cast<const bf16x8*>(&q0);
  r.lo = *reinterpret_cast<const bf16x8*>(&q1);
  return r;
}

__device__ __forceinline__ f32x16 mm3(const HiLo& a, const HiLo& b, f32x16 acc) {
  acc = __builtin_amdgcn_mfma_f32_32x32x16_bf16(a.hi, b.hi, acc, 0, 0, 0);
  acc = __builtin_amdgcn_mfma_f32_32x32x16_bf16(a.hi, b.lo, acc, 0, 0, 0);
  acc = __builtin_amdgcn_mfma_f32_32x32x16_bf16(a.lo, b.hi, acc, 0, 0, 0);
  return acc;
}

// One wave = one 32x32 tile step range. pa/pb pre-offset by row*ld + koff.
// Named E/O pipeline slots (no runtime-indexed arrays); 2-step lookahead.
// Takes acc input so multi-segment K (action|hidden) can chain.
template <int NK, bool SA, bool SB>
__device__ __forceinline__ f32x16 tileMM(const float* __restrict__ pa,
                                         const float* __restrict__ pb,
                                         f32x16 acc) {
  float4 aE0 = LD4(pa), aE1 = LD4(pa + 4);
  float4 bE0 = LD4(pb), bE1 = LD4(pb + 4);
  float4 aO0, aO1, bO0, bO1;
  if (NK > 1) {
    aO0 = LD4(pa + 16); aO1 = LD4(pa + 20);
    bO0 = LD4(pb + 16); bO1 = LD4(pb + 20);
  }
#pragma unroll
  for (int ks = 0; ks < NK; ++ks) {
    HiLo Af, Bf;
    if ((ks & 1) == 0) {
      Af = SA ? reint8(aE0, aE1) : split8(aE0, aE1);
      Bf = SB ? reint8(bE0, bE1) : split8(bE0, bE1);
      if (ks + 2 < NK) {
        const int k = (ks + 2) * 16;
        aE0 = LD4(pa + k); aE1 = LD4(pa + k + 4);
        bE0 = LD4(pb + k); bE1 = LD4(pb + k + 4);
      }
    } else {
      Af = SA ? reint8(aO0, aO1) : split8(aO0, aO1);
      Bf = SB ? reint8(bO0, bO1) : split8(bO0, bO1);
      if (ks + 2 < NK) {
        const int k = (ks + 2) * 16;
        aO0 = LD4(pa + k); aO1 = LD4(pa + k + 4);
        bO0 = LD4(pb + k); bO1 = LD4(pb + k + 4);
      }
    }
    acc = mm3(Af, Bf, acc);
  }
  return acc;
}

#define ACC_ROW(t, lane) (((t) & 3) + 8 * ((t) >> 2) + 4 * ((lane) >> 5))

// ---------------- 1. fused: GRU GEMM | memory^T pre-split | memory norms ----------------
// blocks [0,768): gi = concat(action,hidden) @ W_ih^T (XCD-grouped swizzle)
// blocks [768,896): memTs (transpose + hi/lo pre-split)
// blocks [896,1408): invm
__global__ __launch_bounds__(64) void k_gmt(const float* __restrict__ action,
                                            const float* __restrict__ hidden,
                                            const float* __restrict__ W_ih,
                                            const float* __restrict__ memory,
                                            float* __restrict__ gi,
                                            float* __restrict__ memTs,
                                            float* __restrict__ invm) {
  __shared__ float tile[32][33];
  const int blk = blockIdx.x;
  const int lane = threadIdx.x;
  if (blk < 768) {
    const int xcd = blk & 7, inner = blk >> 3;
    const int bi = inner & 15;
    const int bc = xcd * 6 + (inner >> 4);
    const int r0 = bi * 32, c0 = bc * 32;
    const int m = lane & 31, koff = (lane >> 5) * 8;
    f32x16 acc;
#pragma unroll
    for (int t = 0; t < 16; ++t) acc[t] = 0.0f;
    const float* Wrow = W_ih + (c0 + m) * 640 + koff;
    acc = tileMM<8, false, false>(action + (r0 + m) * 128 + koff, Wrow, acc);
    acc = tileMM<32, false, false>(hidden + (r0 + m) * 512 + koff, Wrow + 128, acc);
    const int col = c0 + m;
#pragma unroll
    for (int t = 0; t < 16; ++t)
      gi[(r0 + ACC_ROW(t, lane)) * 1536 + col] = acc[t];
  } else if (blk < 896) {
    const int tb = blk - 768;
    const int bx = tb & 7, by = tb >> 3;         // bx: m-tile (0..7), by: b-tile (0..15)
    const int r = lane >> 1, cs = (lane & 1) * 16;
#pragma unroll
    for (int u = 0; u < 4; ++u) {
      const float4 v = LD4(memory + (by * 32 + r) * 256 + bx * 32 + cs + 4 * u);
      tile[r][cs + 4 * u + 0] = v.x;
      tile[r][cs + 4 * u + 1] = v.y;
      tile[r][cs + 4 * u + 2] = v.z;
      tile[r][cs + 4 * u + 3] = v.w;
    }
    __syncthreads();
    const int xx = lane >> 1, g2 = (lane & 1) * 2;
#pragma unroll
    for (int gd = 0; gd < 2; ++gd) {
      const int gg = g2 + gd;
      float4 q0, q1;
      q0.x = tile[8 * gg + 0][xx]; q0.y = tile[8 * gg + 1][xx];
      q0.z = tile[8 * gg + 2][xx]; q0.w = tile[8 * gg + 3][xx];
      q1.x = tile[8 * gg + 4][xx]; q1.y = tile[8 * gg + 5][xx];
      q1.z = tile[8 * gg + 6][xx]; q1.w = tile[8 * gg + 7][xx];
      const HiLo s = split8(q0, q1);
      float* dst = memTs + (bx * 32 + xx) * 512 + (by * 4 + gg) * 8;
      *reinterpret_cast<float4*>(dst)     = *reinterpret_cast<const float4*>(&s.hi);
      *reinterpret_cast<float4*>(dst + 4) = *reinterpret_cast<const float4*>(&s.lo);
    }
  } else {
    const int row = blk - 896;
    const float4 v = LD4(memory + row * 256 + lane * 4);
    float ss = v.x * v.x + v.y * v.y + v.z * v.z + v.w * v.w;
    for (int o = 32; o > 0; o >>= 1) ss += __shfl_down(ss, o);
    if (lane == 0) invm[row] = 1.0f / (sqrtf(ss) + 1e-16f);
  }
}

// ---------------- 2. fused: GRU activation + gate/gamma + sumsq zero ----------------
// one block per batch row b
__global__ __launch_bounds__(256) void k_actgg(const float* __restrict__ gi,
                                               const float* __restrict__ b_ih,
                                               const float* __restrict__ b_hh,
                                               const float* __restrict__ W_gate, const float* __restrict__ b_gate,
                                               const float* __restrict__ W_gamma, const float* __restrict__ b_gamma,
                                               float* __restrict__ h,
                                               float* __restrict__ g, float* __restrict__ gamma,
                                               float* __restrict__ ssr, float* __restrict__ ssw) {
  __shared__ float red[8];
  const int b = blockIdx.x, t = threadIdx.x;
  float hv[2];
#pragma unroll
  for (int u = 0; u < 2; ++u) {
    const int c = t + u * 256;
    const float gr = gi[b * 1536 + c] + b_ih[c] + b_hh[c];
    const float gz = gi[b * 1536 + 512 + c] + b_ih[512 + c] + b_hh[512 + c];
    const float gn = gi[b * 1536 + 1024 + c] + b_ih[1024 + c];
    const float hn = b_hh[1024 + c];
    const float r = 1.0f / (1.0f + expf(-gr));
    const float z = 1.0f / (1.0f + expf(-gz));
    hv[u] = (1.0f - z) * tanhf(gn + r * hn);
    h[b * 512 + c] = hv[u];
  }
  float ag = hv[0] * W_gate[t] + hv[1] * W_gate[t + 256];
  float am = hv[0] * W_gamma[t] + hv[1] * W_gamma[t + 256];
  for (int o = 32; o > 0; o >>= 1) { ag += __shfl_down(ag, o); am += __shfl_down(am, o); }
  const int wid = t >> 6, lane = t & 63;
  if (lane == 0) { red[wid] = ag; red[4 + wid] = am; }
  __syncthreads();
  if (t == 0) {
    const float AG = (red[0] + red[1]) + (red[2] + red[3]);
    const float AM = (red[4] + red[5]) + (red[6] + red[7]);
    g[b] = 1.0f / (1.0f + expf(-(AG + b_gate[0])));
    const float x = AM + b_gamma[0];
    gamma[b] = (x > 0.f) ? (x + log1pf(expf(-x))) : log1pf(expf(x));
    ssr[b] = 0.0f;                       // zero atomic targets for k_heads
    ssw[b] = 0.0f;
  }
}

// ---------------- 3. heads GEMM + key-row sum-of-squares (atomic) ----------------
__global__ __launch_bounds__(64) void k_heads(const float* __restrict__ h,
                                              const float* __restrict__ W_read, const float* __restrict__ b_read,
                                              const float* __restrict__ W_write, const float* __restrict__ b_write,
                                              const float* __restrict__ W_shift, const float* __restrict__ b_shift,
                                              float* __restrict__ heads,
                                              float* __restrict__ ssr, float* __restrict__ ssw) {
  const int lane = threadIdx.x;
  const int wg = blockIdx.x;                 // 0..511
  const int xcd = wg & 7, inner = wg >> 3;
  const int bi = inner & 15;
  const int bn = xcd * 4 + (inner >> 4);
  const int r0 = bi * 32, n0 = bn * 32;
  const float* W;
  const float* bias;
  if (n0 < 256)      { W = W_read  + n0 * 512;         bias = b_read  + n0; }
  else if (n0 < 512) { W = W_write + (n0 - 256) * 512; bias = b_write + (n0 - 256); }
  else               { W = W_shift + (n0 - 512) * 512; bias = b_shift + (n0 - 512); }
  const int m = lane & 31, koff = (lane >> 5) * 8;
  f32x16 acc;
#pragma unroll
  for (int t = 0; t < 16; ++t) acc[t] = 0.0f;
  acc = tileMM<32, false, false>(h + (r0 + m) * 512 + koff, W + m * 512 + koff, acc);
  const int col = lane & 31;
  const float bv = bias[col];
#pragma unroll
  for (int t = 0; t < 16; ++t)
    heads[(r0 + ACC_ROW(t, lane)) * 1024 + n0 + col] = acc[t] + bv;
  if (n0 < 512) {
    float* ss = (n0 < 256) ? ssr : ssw;
#pragma unroll
    for (int t = 0; t < 16; ++t) {
      const float v = acc[t] + bv;
      float sq = v * v;
      sq += __shfl_xor(sq, 1);  sq += __shfl_xor(sq, 2);
      sq += __shfl_xor(sq, 4);  sq += __shfl_xor(sq, 8);
      sq += __shfl_xor(sq, 16);
      if ((lane & 31) == 0) atomicAdd(&ss[r0 + ACC_ROW(t, lane)], sq);
    }
  }
}

// ---------------- 4. similarity GEMM ----------------
__global__ __launch_bounds__(64) void k_sim(const float* __restrict__ memory,
                                            const float* __restrict__ heads,
                                            float* __restrict__ simR, float* __restrict__ simW) {
  const int lane = threadIdx.x;
  const int i0 = blockIdx.x * 32;
  const int b0 = blockIdx.y * 32;
  const int seg = blockIdx.z ? 256 : 0;
  float* out = blockIdx.z ? simW : simR;
  const int m = lane & 31, koff = (lane >> 5) * 8;
  f32x16 acc;
#pragma unroll
  for (int t = 0; t < 16; ++t) acc[t] = 0.0f;
  acc = tileMM<16, false, false>(memory + (i0 + m) * 256 + koff,
                                 heads + (b0 + m) * 1024 + seg + koff, acc);
  const int col = lane & 31;
#pragma unroll
  for (int t = 0; t < 16; ++t)
    out[(i0 + ACC_ROW(t, lane)) * 512 + b0 + col] = acc[t];
}

// ---------------- 5. row softmax (+cosine, +gate mix) with TRANSPOSED scattered write ----------------
__global__ __launch_bounds__(256) void k_rowsoft(const float* __restrict__ simR, const float* __restrict__ simW,
                                                 const float* __restrict__ heads,
                                                 const float* __restrict__ invm,
                                                 const float* __restrict__ ssr, const float* __restrict__ ssw,
                                                 const float* __restrict__ g,
                                                 const float* __restrict__ prevR, const float* __restrict__ prevW,
                                                 float* __restrict__ wgrT, float* __restrict__ wgwT,
                                                 float* __restrict__ shiftT) {
  __shared__ float red[8];
  const int row = blockIdx.x, mode = blockIdx.y, t = threadIdx.x;
  float v0, v1;
  if (mode == 2) {
    const float2 s = LD2(heads + row * 1024 + 512 + 2 * t);
    v0 = s.x; v1 = s.y;
  } else {
    const float* sim = mode ? simW : simR;
    const float* ss = mode ? ssw : ssr;
    const float2 s = LD2(sim + row * 512 + 2 * t);
    const float sc = invm[row];
    const float ik0 = 1.0f / (sqrtf(ss[2 * t]) + 1e-16f);
    const float ik1 = 1.0f / (sqrtf(ss[2 * t + 1]) + 1e-16f);
    v0 = s.x * sc * ik0;
    v1 = s.y * sc * ik1;
  }
  float mx = fmaxf(v0, v1);
  for (int o = 32; o > 0; o >>= 1) mx = fmaxf(mx, __shfl_down(mx, o));
  if ((t & 63) == 0) red[t >> 6] = mx;
  __syncthreads();
  mx = fmaxf(fmaxf(red[0], red[1]), fmaxf(red[2], red[3]));
  const float e0 = expf(v0 - mx), e1 = expf(v1 - mx);
  float s2 = e0 + e1;
  for (int o = 32; o > 0; o >>= 1) s2 += __shfl_down(s2, o);
  if ((t & 63) == 0) red[4 + (t >> 6)] = s2;
  __syncthreads();
  const float S = (red[4] + red[5]) + (red[6] + red[7]);
  const float inv = 1.0f / S;
  const float p0 = e0 * inv, p1 = e1 * inv;
  if (mode == 2) {
    shiftT[(2 * t) * 512 + row]     = p0;   // transposed scatter: shiftT[j][b=row]
    shiftT[(2 * t + 1) * 512 + row] = p1;
  } else {
    const float* prev = mode ? prevW : prevR;
    float* outwT = mode ? wgwT : wgrT;
    const float gv = g[row];
    const float2 pr = LD2(prev + row * 512 + 2 * t);
    outwT[(2 * t) * 512 + row]     = gv * p0 + (1.0f - gv) * pr.x;
    outwT[(2 * t + 1) * 512 + row] = gv * p1 + (1.0f - gv) * pr.y;
  }
}

// ---------------- 6. circular conv + sharpen + normalize + transposed write to d_out ----------------
__global__ __launch_bounds__(256) void k_circ(const float* __restrict__ wgrT, const float* __restrict__ wgwT,
                                              const float* __restrict__ shiftT,
                                              const float* __restrict__ gamma,
                                              float* __restrict__ d_out) {
  __shared__ float ls[4][1600];
  const int wid = threadIdx.x >> 6, lane = threadIdx.x & 63;
  const int b = blockIdx.x * 4 + wid;
  const float* wsrc = (blockIdx.y ? wgwT : wgrT) + b * 512;
  const float* ssrc = shiftT + b * 512;
  float* wl = ls[wid];
  float* sl = ls[wid] + 1056;

#pragma unroll
  for (int u = 0; u < 8; ++u) {
    const int k = lane + 64 * u;
    const float v = wsrc[k];
    wl[k + (k >> 5)] = v;
    const int k2 = k + 512;
    wl[k2 + (k2 >> 5)] = v;
    sl[k] = ssrc[k];
  }
  __syncthreads();

  const int i0 = lane * 8;
  float acc[8] = {};
  float win[8];
#pragma unroll
  for (int q = 0; q < 8; ++q) {
    const int a0 = i0 + 512 + q;
    win[q] = wl[a0 + (a0 >> 5)];
  }
  for (int jb = 0; jb < 512; jb += 8) {
    const float4 sA = LD4(&sl[jb]);
    const float4 sB = LD4(&sl[jb + 4]);
    const float sv[8] = {sA.x, sA.y, sA.z, sA.w, sB.x, sB.y, sB.z, sB.w};
#pragma unroll
    for (int u = 0; u < 8; ++u) {
      const float s = sv[u];
#pragma unroll
      for (int t = 0; t < 8; ++t) acc[t] = fmaf(win[(t - u) & 7], s, acc[t]);
      const int na = i0 + 511 - (jb + u);
      win[(7 - u) & 7] = wl[na + (na >> 5)];
    }
  }
  const float4 gm0 = LD4(gamma + i0);
  const float4 gm1 = LD4(gamma + i0 + 4);
  const float ge[8] = {gm0.x, gm0.y, gm0.z, gm0.w, gm1.x, gm1.y, gm1.z, gm1.w};
  float p[8];
  float local = 0.f;
#pragma unroll
  for (int q = 0; q < 8; ++q) { p[q] = powf(acc[q], ge[q]); local += p[q]; }
  for (int o = 32; o > 0; o >>= 1) local += __shfl_down(local, o);
  local = __shfl(local, 0);
  const float inv = 1.0f / local;
  // transposed scatter: out[i][b] = p[i]/csum, rw at +131072, ww at +393216
  float* dst = d_out + 131072 + (blockIdx.y ? 262144 : 0);
#pragma unroll
  for (int q = 0; q < 8; ++q)
    dst[(i0 + q) * 512 + b] = p[q] * inv;
}

// ---------------- 7. read vector: rv = rw @ memory (full K, no atomics) ----------------
__global__ __launch_bounds__(64) void k_readvec(const float* __restrict__ rw,
                                                const float* __restrict__ memTs,
                                                float* __restrict__ rv) {
  const int lane = threadIdx.x;
  const int i0 = blockIdx.x * 32;
  const int m0 = blockIdx.y * 32;
  const int m = lane & 31, koff = (lane >> 5) * 8;
  f32x16 acc;
#pragma unroll
  for (int t = 0; t < 16; ++t) acc[t] = 0.0f;
  acc = tileMM<32, false, true>(rw + (i0 + m) * 512 + koff,
                                memTs + (m0 + m) * 512 + koff, acc);
  const int col = lane & 31;
#pragma unroll
  for (int t = 0; t < 16; ++t)
    rv[(i0 + ACC_ROW(t, lane)) * 256 + m0 + col] = acc[t];
}

// ---------------- launcher: 7 dispatches, no memsets ----------------
extern "C" void kernel_launch(void* const* d_in, const int* in_sizes, int n_in,
                              void* d_out, int out_size, void* d_ws, size_t ws_size,
                              hipStream_t stream) {
  const float* action  = (const float*)d_in[0];
  const float* hidden  = (const float*)d_in[1];
  const float* prevR   = (const float*)d_in[2];
  const float* prevW   = (const float*)d_in[3];
  const float* memory  = (const float*)d_in[4];
  const float* W_ih    = (const float*)d_in[5];
  const float* b_ih    = (const float*)d_in[7];
  const float* b_hh    = (const float*)d_in[8];
  const float* W_read  = (const float*)d_in[9];
  const float* b_read  = (const float*)d_in[10];
  const float* W_write = (const float*)d_in[11];
  const float* b_write = (const float*)d_in[12];
  const float* W_shift = (const float*)d_in[13];
  const float* b_shift = (const float*)d_in[14];
  const float* W_gamma = (const float*)d_in[15];
  const float* b_gamma = (const float*)d_in[16];
  const float* W_gate  = (const float*)d_in[17];
  const float* b_gate  = (const float*)d_in[18];

  float* ws = (float*)d_ws;
  float* out = (float*)d_out;

  k_gmt<<<1408, 64, 0, stream>>>(action, hidden, W_ih, memory,
                                 ws + WS_GI, ws + WS_MEMTS, ws + WS_INVM);
  k_actgg<<<512, 256, 0, stream>>>(ws + WS_GI, b_ih, b_hh,
                                   W_gate, b_gate, W_gamma, b_gamma,
                                   ws + WS_H, ws + WS_G, ws + WS_GAMMA,
                                   ws + WS_SSR, ws + WS_SSW);
  k_heads<<<512, 64, 0, stream>>>(ws + WS_H, W_read, b_read, W_write, b_write,
                                  W_shift, b_shift, ws + WS_HEADS,
                                  ws + WS_SSR, ws + WS_SSW);
  k_sim<<<dim3(16, 16, 2), 64, 0, stream>>>(memory, ws + WS_HEADS, ws + WS_SIMR, ws + WS_SIMW);
  k_rowsoft<<<dim3(512, 3), 256, 0, stream>>>(ws + WS_SIMR, ws + WS_SIMW, ws + WS_HEADS,
                                              ws + WS_INVM, ws + WS_SSR, ws + WS_SSW,
                                              ws + WS_G, prevR, prevW,
                                              ws + WS_WGRT, ws + WS_WGWT, ws + WS_SHIFTT);
  k_circ<<<dim3(128, 2), 256, 0, stream>>>(ws + WS_WGRT, ws + WS_WGWT, ws + WS_SHIFTT,
                                           ws + WS_GAMMA, out);
  k_readvec<<<dim3(16, 8), 64, 0, stream>>>(out + 131072, ws + WS_MEMTS, out);
}